// Round 1
// baseline (2113.073 us; speedup 1.0000x reference)
//
#include <hip/hip_runtime.h>

#define N_NODES 500000
#define N_EDGES 8000000
#define N_GRAPHS 8192

// ---------------- utility ----------------
__global__ void k_fill(float* __restrict__ p, float v, int n) {
    int i = blockIdx.x * 256 + threadIdx.x;
    if (i < n) p[i] = v;
}

// deg[col[e]] += 1  (deg pre-initialized to 1.0 for the self-loop)
__global__ void k_count(const int* __restrict__ col, float* __restrict__ deg, int E) {
    int e = blockIdx.x * 256 + threadIdx.x;
    if (e < E) {
        unsigned c = (unsigned)col[e];
        if (c < N_NODES) atomicAdd(&deg[c], 1.0f);
    }
}

__global__ void k_dinv(const float* __restrict__ deg, float* __restrict__ dinv, int n) {
    int i = blockIdx.x * 256 + threadIdx.x;
    if (i < n) dinv[i] = rsqrtf(deg[i]);
}

// layer-1 node transform: hs = (x @ W1) * dinv ; bufA = bufB = hs
// (bufB starts as hs so the self-loop contribution is already included)
__global__ void k_l1(const float* __restrict__ x, const float* __restrict__ W1,
                     const float* __restrict__ dinv, float* __restrict__ bufA,
                     float* __restrict__ bufB, int n) {
    int v = blockIdx.x * 256 + threadIdx.x;
    if (v >= n) return;
    float xi[9];
#pragma unroll
    for (int k = 0; k < 9; k++) xi[k] = x[v * 9 + k];
    float di = dinv[v];
#pragma unroll
    for (int j = 0; j < 16; j++) {
        float acc = 0.f;
#pragma unroll
        for (int k = 0; k < 9; k++) acc += xi[k] * W1[k * 16 + j];
        acc *= di;
        bufA[v * 16 + j] = acc;
        bufB[v * 16 + j] = acc;
    }
}

// per-edge scatter: dst[col*16+j] += src[row*16+j]; 16 threads per edge
__global__ void k_scatter(const int* __restrict__ row, const int* __restrict__ col,
                          const float* __restrict__ src, float* __restrict__ dst, int E) {
    int t = blockIdx.x * 256 + threadIdx.x;
    int e = t >> 4;
    int j = t & 15;
    if (e < E) {
        unsigned r = (unsigned)row[e];
        unsigned c = (unsigned)col[e];
        if (r < N_NODES && c < N_NODES)
            atomicAdd(&dst[c * 16 + j], src[r * 16 + j]);
    }
}

// layer-2 node transform: h1 = relu(bufB*dinv + b1); hs2 = (h1 @ W2)*dinv;
// bufA = bufB = hs2
__global__ void k_l2(const float* __restrict__ W2, const float* __restrict__ b1,
                     const float* __restrict__ dinv, float* __restrict__ bufA,
                     float* __restrict__ bufB, int n) {
    int v = blockIdx.x * 256 + threadIdx.x;
    if (v >= n) return;
    float di = dinv[v];
    float h1[16];
#pragma unroll
    for (int j = 0; j < 16; j++) {
        float t = bufB[v * 16 + j] * di + b1[j];
        h1[j] = t > 0.f ? t : 0.f;
    }
#pragma unroll
    for (int j = 0; j < 16; j++) {
        float acc = 0.f;
#pragma unroll
        for (int k = 0; k < 16; k++) acc += h1[k] * W2[k * 16 + j];
        acc *= di;
        bufA[v * 16 + j] = acc;
        bufB[v * 16 + j] = acc;
    }
}

// pool: h2 = relu(bufB*dinv + b2); pooled[batch[v]] += h2; cnt[batch[v]] += 1
__global__ void k_pool(const float* __restrict__ bufB, const float* __restrict__ dinv,
                       const float* __restrict__ b2, const int* __restrict__ batch,
                       float* __restrict__ pooled, float* __restrict__ cnt, int n) {
    int v = blockIdx.x * 256 + threadIdx.x;
    if (v >= n) return;
    float di = dinv[v];
    unsigned g = (unsigned)batch[v];
    if (g >= N_GRAPHS) return;
#pragma unroll
    for (int j = 0; j < 16; j++) {
        float t = bufB[v * 16 + j] * di + b2[j];
        t = t > 0.f ? t : 0.f;
        atomicAdd(&pooled[g * 16 + j], t);
    }
    atomicAdd(&cnt[g], 1.0f);
}

// head: emb = pooled/max(cnt,1); z=[emb,meta]; out = relu(z@Wh1+bh1)@Wh2+bh2
__global__ void k_head(const float* __restrict__ pooled, const float* __restrict__ cnt,
                       const float* __restrict__ meta, const float* __restrict__ Wh1,
                       const float* __restrict__ bh1, const float* __restrict__ Wh2,
                       const float* __restrict__ bh2, float* __restrict__ out, int G) {
    int g = blockIdx.x * 256 + threadIdx.x;
    if (g >= G) return;
    float z[43];
    float c = cnt[g];
    c = c > 1.f ? c : 1.f;
#pragma unroll
    for (int j = 0; j < 16; j++) z[j] = pooled[g * 16 + j] / c;
#pragma unroll
    for (int j = 0; j < 27; j++) z[16 + j] = meta[g * 27 + j];
    float acc2 = bh2[0];
#pragma unroll
    for (int jj = 0; jj < 16; jj++) {
        float a = bh1[jj];
#pragma unroll
        for (int k = 0; k < 43; k++) a += z[k] * Wh1[k * 16 + jj];
        a = a > 0.f ? a : 0.f;
        acc2 += a * Wh2[jj];
    }
    out[g] = acc2;
}

extern "C" void kernel_launch(void* const* d_in, const int* in_sizes, int n_in,
                              void* d_out, int out_size, void* d_ws, size_t ws_size,
                              hipStream_t stream) {
    const float* x    = (const float*)d_in[0];
    const int*   ei   = (const int*)d_in[1];   // [2, E] row-major: row then col
    const int*   batch= (const int*)d_in[2];
    const float* meta = (const float*)d_in[3];
    const float* W1   = (const float*)d_in[4];
    const float* b1   = (const float*)d_in[5];
    const float* W2   = (const float*)d_in[6];
    const float* b2   = (const float*)d_in[7];
    const float* Wh1  = (const float*)d_in[8];
    const float* bh1  = (const float*)d_in[9];
    const float* Wh2  = (const float*)d_in[10];
    const float* bh2  = (const float*)d_in[11];
    float* out = (float*)d_out;

    const int N = N_NODES, E = N_EDGES, G = N_GRAPHS;
    const int* row = ei;
    const int* col = ei + E;

    // workspace layout (floats)
    float* ws     = (float*)d_ws;
    float* dinv   = ws;                 // N
    float* bufA   = ws + 500000;        // N*16 (2MB offset: 16B aligned)
    float* bufB   = bufA + 8000000;     // N*16
    float* pooled = bufB + 8000000;     // G*16
    float* cnt    = pooled + G * 16;    // G

    dim3 blk(256);
    int gN  = (N + 255) / 256;
    int gE  = (E + 255) / 256;
    int gE16 = (E * 16 + 255) / 256;  // 16 threads per edge (fits in int: 128M)

    // degree (stored in bufA temporarily), init 1.0 for self-loop
    k_fill<<<gN, blk, 0, stream>>>(bufA, 1.0f, N);
    // zero pooled + cnt (contiguous G*17)
    k_fill<<<(G * 17 + 255) / 256, blk, 0, stream>>>(pooled, 0.0f, G * 17);
    k_count<<<gE, blk, 0, stream>>>(col, bufA, E);
    k_dinv<<<gN, blk, 0, stream>>>(bufA, dinv, N);

    // layer 1
    k_l1<<<gN, blk, 0, stream>>>(x, W1, dinv, bufA, bufB, N);
    k_scatter<<<gE16, blk, 0, stream>>>(row, col, bufA, bufB, E);

    // layer 2
    k_l2<<<gN, blk, 0, stream>>>(W2, b1, dinv, bufA, bufB, N);
    k_scatter<<<gE16, blk, 0, stream>>>(row, col, bufA, bufB, E);

    // pool + head
    k_pool<<<gN, blk, 0, stream>>>(bufB, dinv, b2, batch, pooled, cnt, N);
    k_head<<<(G + 255) / 256, blk, 0, stream>>>(pooled, cnt, meta, Wh1, bh1, Wh2, bh2, out, G);
}

// Round 2
// 1449.579 us; speedup vs baseline: 1.4577x; 1.4577x over previous
//
#include <hip/hip_runtime.h>

#define N_NODES 500000
#define N_EDGES 8000000
#define N_GRAPHS 8192
#define POOL_CH 128   // nodes per serial chunk in k_pool2

// ---------------- utility ----------------
__global__ void k_fill(float* __restrict__ p, float v, int n) {
    int i = blockIdx.x * 256 + threadIdx.x;
    if (i < n) p[i] = v;
}

// deg[col[e]] += 1  (deg pre-initialized to 1.0 for the self-loop)
__global__ void k_count(const int* __restrict__ col, float* __restrict__ deg, int E) {
    int e = blockIdx.x * 256 + threadIdx.x;
    if (e < E) {
        unsigned c = (unsigned)col[e];
        if (c < N_NODES) atomicAdd(&deg[c], 1.0f);
    }
}

__global__ void k_dinv(const float* __restrict__ deg, float* __restrict__ dinv, int n) {
    int i = blockIdx.x * 256 + threadIdx.x;
    if (i < n) dinv[i] = rsqrtf(deg[i]);
}

// layer-1 node transform: hs = (x @ W1) * dinv ; bufA = bufB = hs
__global__ void k_l1(const float* __restrict__ x, const float* __restrict__ W1,
                     const float* __restrict__ dinv, float* __restrict__ bufA,
                     float* __restrict__ bufB, int n) {
    int v = blockIdx.x * 256 + threadIdx.x;
    if (v >= n) return;
    float xi[9];
#pragma unroll
    for (int k = 0; k < 9; k++) xi[k] = x[v * 9 + k];
    float di = dinv[v];
#pragma unroll
    for (int j = 0; j < 16; j++) {
        float acc = 0.f;
#pragma unroll
        for (int k = 0; k < 9; k++) acc += xi[k] * W1[k * 16 + j];
        acc *= di;
        bufA[v * 16 + j] = acc;
        bufB[v * 16 + j] = acc;
    }
}

// per-edge scatter: dst[col*16+j] += src[row*16+j]; 16 threads per edge
__global__ void k_scatter(const int* __restrict__ row, const int* __restrict__ col,
                          const float* __restrict__ src, float* __restrict__ dst, int E) {
    int t = blockIdx.x * 256 + threadIdx.x;
    int e = t >> 4;
    int j = t & 15;
    if (e < E) {
        unsigned r = (unsigned)row[e];
        unsigned c = (unsigned)col[e];
        if (r < N_NODES && c < N_NODES)
            atomicAdd(&dst[c * 16 + j], src[r * 16 + j]);
    }
}

// layer-2 node transform
__global__ void k_l2(const float* __restrict__ W2, const float* __restrict__ b1,
                     const float* __restrict__ dinv, float* __restrict__ bufA,
                     float* __restrict__ bufB, int n) {
    int v = blockIdx.x * 256 + threadIdx.x;
    if (v >= n) return;
    float di = dinv[v];
    float h1[16];
#pragma unroll
    for (int j = 0; j < 16; j++) {
        float t = bufB[v * 16 + j] * di + b1[j];
        h1[j] = t > 0.f ? t : 0.f;
    }
#pragma unroll
    for (int j = 0; j < 16; j++) {
        float acc = 0.f;
#pragma unroll
        for (int k = 0; k < 16; k++) acc += h1[k] * W2[k * 16 + j];
        acc *= di;
        bufA[v * 16 + j] = acc;
        bufB[v * 16 + j] = acc;
    }
}

// pool, exploiting sorted batch: 16 lanes (one per feature) walk POOL_CH
// consecutive nodes, accumulate in a register while graph id is unchanged,
// flush one atomic per (graph boundary, feature). ~200k atomics vs 8.5M.
__global__ void k_pool2(const float* __restrict__ bufB, const float* __restrict__ dinv,
                        const float* __restrict__ b2, const int* __restrict__ batch,
                        float* __restrict__ pooled, float* __restrict__ cnt, int n) {
    int tid = blockIdx.x * 256 + threadIdx.x;
    int chunk = tid >> 4;
    int j = tid & 15;
    int start = chunk * POOL_CH;
    if (start >= n) return;
    int end = start + POOL_CH;
    if (end > n) end = n;
    float bj = b2[j];
    int g_cur = batch[start];
    float acc = 0.f;
    float c_acc = 0.f;
    for (int v = start; v < end; v++) {
        int g = batch[v];
        if (g != g_cur) {
            atomicAdd(&pooled[g_cur * 16 + j], acc);
            if (j == 0) atomicAdd(&cnt[g_cur], c_acc);
            acc = 0.f; c_acc = 0.f; g_cur = g;
        }
        float t = bufB[v * 16 + j] * dinv[v] + bj;
        acc += t > 0.f ? t : 0.f;
        c_acc += 1.f;
    }
    atomicAdd(&pooled[g_cur * 16 + j], acc);
    if (j == 0) atomicAdd(&cnt[g_cur], c_acc);
}

// head: emb = pooled/max(cnt,1); z=[emb,meta]; out = relu(z@Wh1+bh1)@Wh2+bh2
__global__ void k_head(const float* __restrict__ pooled, const float* __restrict__ cnt,
                       const float* __restrict__ meta, const float* __restrict__ Wh1,
                       const float* __restrict__ bh1, const float* __restrict__ Wh2,
                       const float* __restrict__ bh2, float* __restrict__ out, int G) {
    int g = blockIdx.x * 256 + threadIdx.x;
    if (g >= G) return;
    float z[43];
    float c = cnt[g];
    c = c > 1.f ? c : 1.f;
#pragma unroll
    for (int j = 0; j < 16; j++) z[j] = pooled[g * 16 + j] / c;
#pragma unroll
    for (int j = 0; j < 27; j++) z[16 + j] = meta[g * 27 + j];
    float acc2 = bh2[0];
#pragma unroll
    for (int jj = 0; jj < 16; jj++) {
        float a = bh1[jj];
#pragma unroll
        for (int k = 0; k < 43; k++) a += z[k] * Wh1[k * 16 + jj];
        a = a > 0.f ? a : 0.f;
        acc2 += a * Wh2[jj];
    }
    out[g] = acc2;
}

extern "C" void kernel_launch(void* const* d_in, const int* in_sizes, int n_in,
                              void* d_out, int out_size, void* d_ws, size_t ws_size,
                              hipStream_t stream) {
    const float* x    = (const float*)d_in[0];
    const int*   ei   = (const int*)d_in[1];   // [2, E]: row then col
    const int*   batch= (const int*)d_in[2];
    const float* meta = (const float*)d_in[3];
    const float* W1   = (const float*)d_in[4];
    const float* b1   = (const float*)d_in[5];
    const float* W2   = (const float*)d_in[6];
    const float* b2   = (const float*)d_in[7];
    const float* Wh1  = (const float*)d_in[8];
    const float* bh1  = (const float*)d_in[9];
    const float* Wh2  = (const float*)d_in[10];
    const float* bh2  = (const float*)d_in[11];
    float* out = (float*)d_out;

    const int N = N_NODES, E = N_EDGES, G = N_GRAPHS;
    const int* row = ei;
    const int* col = ei + E;

    // workspace layout (floats)
    float* ws     = (float*)d_ws;
    float* dinv   = ws;                 // N
    float* bufA   = ws + 500000;        // N*16
    float* bufB   = bufA + 8000000;     // N*16
    float* pooled = bufB + 8000000;     // G*16
    float* cnt    = pooled + G * 16;    // G

    dim3 blk(256);
    int gN   = (N + 255) / 256;
    int gE   = (E + 255) / 256;
    int gE16 = (E * 16 + 255) / 256;

    // degree (in bufA temporarily), init 1.0 for self-loop
    k_fill<<<gN, blk, 0, stream>>>(bufA, 1.0f, N);
    // zero pooled + cnt (contiguous G*17)
    k_fill<<<(G * 17 + 255) / 256, blk, 0, stream>>>(pooled, 0.0f, G * 17);
    k_count<<<gE, blk, 0, stream>>>(col, bufA, E);
    k_dinv<<<gN, blk, 0, stream>>>(bufA, dinv, N);

    // layer 1
    k_l1<<<gN, blk, 0, stream>>>(x, W1, dinv, bufA, bufB, N);
    k_scatter<<<gE16, blk, 0, stream>>>(row, col, bufA, bufB, E);

    // layer 2
    k_l2<<<gN, blk, 0, stream>>>(W2, b1, dinv, bufA, bufB, N);
    k_scatter<<<gE16, blk, 0, stream>>>(row, col, bufA, bufB, E);

    // pool + head
    int chunks = (N + POOL_CH - 1) / POOL_CH;
    int gP = (chunks * 16 + 255) / 256;
    k_pool2<<<gP, blk, 0, stream>>>(bufB, dinv, b2, batch, pooled, cnt, N);
    k_head<<<(G + 255) / 256, blk, 0, stream>>>(pooled, cnt, meta, Wh1, bh1, Wh2, bh2, out, G);
}